// Round 3
// baseline (142.034 us; speedup 1.0000x reference)
//
#include <hip/hip_runtime.h>
#include <math.h>

#define LL 8
#define AA 4
#define DD 256
#define KF 129            // frequencies 0..128
#define KH 128            // complex path handles k=0..127; k=128 is real
#define NCHUNK 512
#define CLEN 32           // 16384 / 512
#define NGRP 64           // groups after kcomb (512 / 8)
#define NE 44             // stored complex entries per operator (rows 1..8)
#define NE1 45            // including implicit row 0
#define NODE_STRIDE 47    // LDS node stride in v2f (94 dwords -> 2-way banks, free)

#define IDX(l,l1) ((((l)*((l)+1))/2) + (l1))

typedef float v2f __attribute__((ext_vector_type(2)));

// ws layout in floats (~26 MB)
#define Q_OFF   0
#define OPS_OFF (Q_OFF + 32*KF*2)                 // 8,256
#define S1_OFF  (OPS_OFF + NCHUNK*NE*KH*2)        // + 5,767,168
#define R0_OFF  (S1_OFF + NGRP*NE*KH*2)           // +   720,896
#define R1_OFF  (R0_OFF + NE*NCHUNK)              // +    22,528
#define V_OFF   (R1_OFF + NE*NGRP)                // +     2,816

#define TWO_PI_256 0.0245436926061702596754894014319f

// ---------------- complex helpers (packed fp32) ----------------------------------------------
__device__ __forceinline__ v2f vswap(v2f a) { return __builtin_shufflevector(a, a, 1, 0); }

// A <- B * A (9x9 unit-row0 lower-triangular complex, packed)
__device__ __forceinline__ void cmatmul(v2f (&A)[NE1], const v2f (&B)[NE1]) {
#pragma unroll
  for (int l2 = LL; l2 >= 1; --l2) {
    v2f C[LL + 1];
#pragma unroll
    for (int l1 = 0; l1 <= l2; ++l1) C[l1] = (v2f){0.0f, 0.0f};
#pragma unroll
    for (int m = 0; m <= l2; ++m) {
      const v2f bm = B[IDX(l2, m)];
      const float bs = bm.x;
      const v2f bn = {-bm.y, bm.y};
#pragma unroll
      for (int l1 = 0; l1 <= m; ++l1) {
        const v2f Am = A[IDX(m, l1)];
        C[l1] += bs * Am;
        C[l1] += bn * vswap(Am);
      }
    }
#pragma unroll
    for (int l1 = 0; l1 <= l2; ++l1) A[IDX(l2, l1)] = C[l1];
  }
}

// A <- B * A (real)
__device__ __forceinline__ void rmatmul(float (&A)[NE1], const float (&B)[NE1]) {
#pragma unroll
  for (int l2 = LL; l2 >= 1; --l2) {
    float C[LL + 1];
#pragma unroll
    for (int l1 = 0; l1 <= l2; ++l1) C[l1] = 0.0f;
#pragma unroll
    for (int m = 0; m <= l2; ++m) {
      const float bs = B[IDX(l2, m)];
#pragma unroll
      for (int l1 = 0; l1 <= m; ++l1) C[l1] = fmaf(bs, A[IDX(m, l1)], C[l1]);
    }
#pragma unroll
    for (int l1 = 0; l1 <= l2; ++l1) A[IDX(l2, l1)] = C[l1];
  }
}

// ---------------- kernel 0: Q[l][c][k] = (2*sigmoid-1) * DFT_k(softmax(hash_emb[l,c,:])) ------
__global__ __launch_bounds__(256) void kq(const float* __restrict__ hemb,
                                          const float* __restrict__ slog,
                                          float* __restrict__ Q) {
  const int b = blockIdx.x;   // b = l*4 + c
  const int t = threadIdx.x;  // 0..255
  __shared__ float sh[DD], tc[DD], ts[DD], red[256];
  {
    float sn, cs;
    __sincosf((float)t * TWO_PI_256, &sn, &cs);
    tc[t] = cs; ts[t] = sn;
  }
  float h = hemb[b * DD + t];
  red[t] = h; __syncthreads();
  for (int off = 128; off > 0; off >>= 1) {
    if (t < off) red[t] = fmaxf(red[t], red[t + off]);
    __syncthreads();
  }
  float mx = red[0]; __syncthreads();
  float e = __expf(h - mx);
  red[t] = e; __syncthreads();
  for (int off = 128; off > 0; off >>= 1) {
    if (t < off) red[t] += red[t + off];
    __syncthreads();
  }
  float s = red[0];
  sh[t] = e / s;
  __syncthreads();
  if (t < KF) {
    float cr = 0.0f, ci = 0.0f;
    for (int j = 0; j < DD; ++j) {
      const int m = (t * j) & 255;
      const float p = sh[j];
      cr = fmaf(p, tc[m], cr);
      ci = fmaf(p, ts[m], ci);     // ci accumulates +sum p*sin; negate at store
    }
    const float sl = slog[b];
    const float sg = 1.0f / (1.0f + __expf(-sl));
    const float q = fmaf(2.0f, sg, -1.0f);
    ((v2f*)Q)[b * KF + t] = (v2f){q * cr, -q * ci};
  }
}

// ---------------- per-step operator update (complex, packed) ---------------------------------
template <int CC>
__device__ __forceinline__ void cstep(v2f (&G)[NE1], const v2f (&Qv)[LL * AA],
                                      const float (&z)[LL + 1]) {
#pragma unroll
  for (int l = LL; l >= 1; --l) {          // descending: row l reads OLD row l-1
    const float zl = z[l], oz = 1.0f - zl;
    const v2f zq = zl * Qv[(l - 1) * AA + CC];
    const float zqx = zq.x;
    const v2f zqn = {-zq.y, zq.y};
    G[IDX(l, l)] *= oz;
#pragma unroll
    for (int l1 = 0; l1 < l; ++l1) {
      const v2f H = G[IDX(l - 1, l1)];
      v2f tv = oz * G[IDX(l, l1)];
      tv += zqx * H;
      tv += zqn * vswap(H);
      G[IDX(l, l1)] = tv;
    }
  }
}

__device__ __forceinline__ void rstep(float (&G)[NE1], const float (&Qs)[LL],
                                      const float (&z)[LL + 1]) {
#pragma unroll
  for (int l = LL; l >= 1; --l) {
    const float zl = z[l], oz = 1.0f - zl;
    const float zq = zl * Qs[l - 1];
    G[IDX(l, l)] *= oz;
#pragma unroll
    for (int l1 = 0; l1 < l; ++l1)
      G[IDX(l, l1)] = fmaf(zq, G[IDX(l - 1, l1)], oz * G[IDX(l, l1)]);
  }
}

// ---------------- kernel 1: chunk transfer operators -----------------------------------------
__global__ __launch_bounds__(64) void kchunk(const int* __restrict__ seq,
                                             const float* __restrict__ Qf,
                                             float* __restrict__ ops,
                                             float* __restrict__ ops128) {
  const int blk = blockIdx.x;
  const int t = threadIdx.x;
  if (blk < NCHUNK * 2) {
    const int p = blk >> 1;
    const int k = (blk & 1) * 64 + t;     // 0..127
    const v2f* Q2 = (const v2f*)Qf;
    v2f Qv[LL * AA];
#pragma unroll
    for (int lc = 0; lc < LL * AA; ++lc) Qv[lc] = Q2[lc * KF + k];
    v2f G[NE1];
#pragma unroll
    for (int e = 0; e < NE1; ++e) G[e] = (v2f){0.0f, 0.0f};
#pragma unroll
    for (int l = 0; l <= LL; ++l) G[IDX(l, l)] = (v2f){1.0f, 0.0f};

    const int base = p * CLEN;
    const int4* sq = (const int4*)(seq + base);
#pragma unroll 1
    for (int q4 = 0; q4 < CLEN / 4; ++q4) {
      const int4 cv = sq[q4];
      const int cc[4] = {cv.x, cv.y, cv.z, cv.w};
#pragma unroll
      for (int r = 0; r < 4; ++r) {
        const int i = base + q4 * 4 + r;
        const float inv = 1.0f / (float)(i + 1);
        float z[LL + 1];
        z[0] = 0.0f;
#pragma unroll
        for (int l = 1; l <= LL; ++l) z[l] = (float)l * inv;
        if (i + 1 < LL) {                 // uniform; true only for chunk 0 steps 0..6
#pragma unroll
          for (int l = 1; l <= LL; ++l) if (l > i + 1) z[l] = 0.0f;
        }
        switch (cc[r]) {
          case 0:  cstep<0>(G, Qv, z); break;
          case 1:  cstep<1>(G, Qv, z); break;
          case 2:  cstep<2>(G, Qv, z); break;
          default: cstep<3>(G, Qv, z); break;
        }
      }
    }
    v2f* O2 = (v2f*)ops;
#pragma unroll
    for (int e = 0; e < NE; ++e) O2[((size_t)p * NE + e) * KH + k] = G[e + 1];
  } else {
    // k = 128 (Nyquist, real Q); lane = chunk
    const int p = (blk - NCHUNK * 2) * 64 + t;   // 0..511
    float Q8[LL * AA];
#pragma unroll
    for (int lc = 0; lc < LL * AA; ++lc) Q8[lc] = Qf[(lc * KF + KH) * 2];
    float G[NE1];
#pragma unroll
    for (int e = 0; e < NE1; ++e) G[e] = 0.0f;
#pragma unroll
    for (int l = 0; l <= LL; ++l) G[IDX(l, l)] = 1.0f;

    const int base = p * CLEN;
    for (int s2 = 0; s2 < CLEN; ++s2) {
      const int i = base + s2;            // per-lane
      const int c = seq[i];
      const float inv = 1.0f / (float)(i + 1);
      float z[LL + 1];
      z[0] = 0.0f;
#pragma unroll
      for (int l = 1; l <= LL; ++l) z[l] = (l <= i + 1) ? (float)l * inv : 0.0f;
      float Qs[LL];
#pragma unroll
      for (int l = 0; l < LL; ++l) {
        const float qa = (c & 1) ? Q8[l * AA + 1] : Q8[l * AA + 0];
        const float qb = (c & 1) ? Q8[l * AA + 3] : Q8[l * AA + 2];
        Qs[l] = (c & 2) ? qb : qa;
      }
      rstep(G, Qs, z);
    }
#pragma unroll
    for (int e = 0; e < NE; ++e) ops128[e * NCHUNK + p] = G[e + 1];
  }
}

// ---------------- kernel 2: serial combine 8 consecutive ops (512 -> 64) ----------------------
__global__ __launch_bounds__(64) void kcomb(const float* __restrict__ in,
                                            float* __restrict__ out,
                                            const float* __restrict__ in128,
                                            float* __restrict__ out128) {
  const int blk = blockIdx.x;
  const int t = threadIdx.x;
  if (blk < 128) {
    const int g = blk >> 1;
    const int k = (blk & 1) * 64 + t;
    const v2f* I2 = (const v2f*)in;
    v2f A[NE1];
    A[0] = (v2f){1.0f, 0.0f};
#pragma unroll
    for (int e = 0; e < NE; ++e) A[e + 1] = I2[((size_t)(g * 8) * NE + e) * KH + k];
#pragma unroll 1
    for (int j = 1; j < 8; ++j) {
      v2f B[NE1];
      B[0] = (v2f){1.0f, 0.0f};
#pragma unroll
      for (int e = 0; e < NE; ++e) B[e + 1] = I2[((size_t)(g * 8 + j) * NE + e) * KH + k];
      cmatmul(A, B);
    }
    v2f* O2 = (v2f*)out;
#pragma unroll
    for (int e = 0; e < NE; ++e) O2[((size_t)g * NE + e) * KH + k] = A[e + 1];
  } else {
    const int g = t;                      // 0..63
    float A[NE1];
    A[0] = 1.0f;
#pragma unroll
    for (int e = 0; e < NE; ++e) A[e + 1] = in128[e * NCHUNK + g * 8];
#pragma unroll 1
    for (int j = 1; j < 8; ++j) {
      float B[NE1];
      B[0] = 1.0f;
#pragma unroll
      for (int e = 0; e < NE; ++e) B[e + 1] = in128[e * NCHUNK + g * 8 + j];
      rmatmul(A, B);
    }
#pragma unroll
    for (int e = 0; e < NE; ++e) out128[e * NGRP + g] = A[e + 1];
  }
}

// ---------------- kernel 3: per-k in-LDS binary tree over 64 ops; emit v_k = root[L][0] -------
__global__ __launch_bounds__(64) void ktree(const float* __restrict__ in,
                                            const float* __restrict__ in128,
                                            float* __restrict__ v) {
  const int blk = blockIdx.x;
  const int t = threadIdx.x;
  __shared__ v2f nodes[NGRP][NODE_STRIDE];
  if (blk < KH) {
    const int k = blk;
    const v2f* I2 = (const v2f*)in;
    {
      v2f A[NE1];
      A[0] = (v2f){1.0f, 0.0f};
#pragma unroll
      for (int e = 0; e < NE; ++e) A[e + 1] = I2[((size_t)t * NE + e) * KH + k];
#pragma unroll
      for (int e = 0; e < NE1; ++e) nodes[t][e] = A[e];
    }
    __syncthreads();
    for (int n = NGRP; n > 1; n >>= 1) {
      const int half = n >> 1;
      v2f A[NE1], B[NE1];
      const bool act = (t < half);
      if (act) {
#pragma unroll
        for (int e = 0; e < NE1; ++e) { A[e] = nodes[2 * t][e]; B[e] = nodes[2 * t + 1][e]; }
      }
      __syncthreads();
      if (act) {
        cmatmul(A, B);                     // A <- B*A (later * earlier)
#pragma unroll
        for (int e = 0; e < NE1; ++e) nodes[t][e] = A[e];
      }
      __syncthreads();
    }
    if (t == 0) ((v2f*)v)[k] = nodes[0][IDX(LL, 0)];
  } else {
    float* fl = (float*)&nodes[0][0];      // real tree, node stride 2*NODE_STRIDE floats
    const int NS = 2 * NODE_STRIDE;
    {
      float A[NE1];
      A[0] = 1.0f;
#pragma unroll
      for (int e = 0; e < NE; ++e) A[e + 1] = in128[e * NGRP + t];
#pragma unroll
      for (int e = 0; e < NE1; ++e) fl[t * NS + e] = A[e];
    }
    __syncthreads();
    for (int n = NGRP; n > 1; n >>= 1) {
      const int half = n >> 1;
      float A[NE1], B[NE1];
      const bool act = (t < half);
      if (act) {
#pragma unroll
        for (int e = 0; e < NE1; ++e) { A[e] = fl[2 * t * NS + e]; B[e] = fl[(2 * t + 1) * NS + e]; }
      }
      __syncthreads();
      if (act) {
        rmatmul(A, B);
#pragma unroll
        for (int e = 0; e < NE1; ++e) fl[t * NS + e] = A[e];
      }
      __syncthreads();
    }
    if (t == 0) ((v2f*)v)[KH] = (v2f){fl[IDX(LL, 0)], 0.0f};
  }
}

// ---------------- kernel 4: inverse real DFT --------------------------------------------------
__global__ __launch_bounds__(256) void kdft(const float* __restrict__ v,
                                            float* __restrict__ out) {
  const int t = threadIdx.x;
  __shared__ float tc[DD], ts[DD], vr[KF], vi[KF];
  {
    float sn, cs;
    __sincosf((float)t * TWO_PI_256, &sn, &cs);
    tc[t] = cs; ts[t] = sn;
  }
  if (t < KF) {
    v2f vv = ((const v2f*)v)[t];
    vr[t] = vv.x; vi[t] = vv.y;
  }
  __syncthreads();
  float sum = vr[0] + ((t & 1) ? -vr[KH] : vr[KH]);
  for (int k2 = 1; k2 < KH; ++k2) {
    const int m = (t * k2) & 255;
    sum = fmaf(2.0f * vr[k2], tc[m], sum);
    sum = fmaf(-2.0f * vi[k2], ts[m], sum);
  }
  out[t] = sum * (1.0f / 256.0f);
}

extern "C" void kernel_launch(void* const* d_in, const int* in_sizes, int n_in,
                              void* d_out, int out_size, void* d_ws, size_t ws_size,
                              hipStream_t stream) {
  (void)in_sizes; (void)n_in; (void)out_size; (void)ws_size;
  const int*   seq  = (const int*)d_in[0];
  const float* hemb = (const float*)d_in[1];
  const float* slog = (const float*)d_in[2];
  float* ws  = (float*)d_ws;
  float* Q   = ws + Q_OFF;
  float* ops = ws + OPS_OFF;
  float* s1  = ws + S1_OFF;
  float* r0  = ws + R0_OFF;
  float* r1  = ws + R1_OFF;
  float* vv  = ws + V_OFF;
  float* o   = (float*)d_out;

  hipLaunchKernelGGL(kq,     dim3(LL * AA), dim3(256), 0, stream, hemb, slog, Q);
  hipLaunchKernelGGL(kchunk, dim3(NCHUNK * 2 + NCHUNK / 64), dim3(64), 0, stream, seq, Q, ops, r0);
  hipLaunchKernelGGL(kcomb,  dim3(129), dim3(64), 0, stream, ops, s1, r0, r1);
  hipLaunchKernelGGL(ktree,  dim3(129), dim3(64), 0, stream, s1, r1, vv);
  hipLaunchKernelGGL(kdft,   dim3(1), dim3(256), 0, stream, vv, o);
}

// Round 4
// 133.374 us; speedup vs baseline: 1.0649x; 1.0649x over previous
//
#include <hip/hip_runtime.h>
#include <math.h>

#define LL 8
#define AA 4
#define DD 256
#define KF 129            // frequencies 0..128
#define KH 128            // complex path handles k=0..127; k=128 is real
#define NCHUNK 512
#define CLEN 32           // 16384 / 512
#define NGRP 64           // groups after kcomb (512 / 8)
#define NE 44             // stored complex entries per operator (rows 1..8)
#define NE1 45            // including implicit row 0

#define IDX(l,l1) ((((l)*((l)+1))/2) + (l1))

typedef float v2f __attribute__((ext_vector_type(2)));

// ws layout in floats (~26 MB)
#define Q_OFF   0
#define OPS_OFF (Q_OFF + 32*KF*2)                 // 8,256
#define S1_OFF  (OPS_OFF + NCHUNK*NE*KH*2)        // + 5,767,168
#define R0_OFF  (S1_OFF + NGRP*NE*KH*2)           // +   720,896
#define R1_OFF  (R0_OFF + NE*NCHUNK)              // +    22,528
#define V_OFF   (R1_OFF + NE*NGRP)                // +     2,816

#define TWO_PI_256 0.0245436926061702596754894014319f

// ---------------- complex helpers (packed fp32) ----------------------------------------------
__device__ __forceinline__ v2f vswap(v2f a) { return __builtin_shufflevector(a, a, 1, 0); }

// A <- B * A (9x9 unit-row0 lower-triangular complex)
__device__ __forceinline__ void cmatmul(v2f (&A)[NE1], const v2f (&B)[NE1]) {
#pragma unroll
  for (int l2 = LL; l2 >= 1; --l2) {
    v2f C[LL + 1];
#pragma unroll
    for (int l1 = 0; l1 <= l2; ++l1) C[l1] = (v2f){0.0f, 0.0f};
#pragma unroll
    for (int m = 0; m <= l2; ++m) {
      const v2f bm = B[IDX(l2, m)];
      const float bs = bm.x;
      const v2f bn = {-bm.y, bm.y};
#pragma unroll
      for (int l1 = 0; l1 <= m; ++l1) {
        const v2f Am = A[IDX(m, l1)];
        C[l1] += bs * Am;
        C[l1] += bn * vswap(Am);
      }
    }
#pragma unroll
    for (int l1 = 0; l1 <= l2; ++l1) A[IDX(l2, l1)] = C[l1];
  }
}

// A <- B * A (real)
__device__ __forceinline__ void rmatmul(float (&A)[NE1], const float (&B)[NE1]) {
#pragma unroll
  for (int l2 = LL; l2 >= 1; --l2) {
    float C[LL + 1];
#pragma unroll
    for (int l1 = 0; l1 <= l2; ++l1) C[l1] = 0.0f;
#pragma unroll
    for (int m = 0; m <= l2; ++m) {
      const float bs = B[IDX(l2, m)];
#pragma unroll
      for (int l1 = 0; l1 <= m; ++l1) C[l1] = fmaf(bs, A[IDX(m, l1)], C[l1]);
    }
#pragma unroll
    for (int l1 = 0; l1 <= l2; ++l1) A[IDX(l2, l1)] = C[l1];
  }
}

// ---------------- kernel 0: Q[l][c][k] = (2*sigmoid-1) * DFT_k(softmax(hash_emb[l,c,:])) ------
__global__ __launch_bounds__(256) void kq(const float* __restrict__ hemb,
                                          const float* __restrict__ slog,
                                          float* __restrict__ Q) {
  const int b = blockIdx.x;   // b = l*4 + c
  const int t = threadIdx.x;  // 0..255
  __shared__ float sh[DD], tc[DD], ts[DD], red[256];
  {
    float sn, cs;
    __sincosf((float)t * TWO_PI_256, &sn, &cs);
    tc[t] = cs; ts[t] = sn;
  }
  float h = hemb[b * DD + t];
  red[t] = h; __syncthreads();
  for (int off = 128; off > 0; off >>= 1) {
    if (t < off) red[t] = fmaxf(red[t], red[t + off]);
    __syncthreads();
  }
  float mx = red[0]; __syncthreads();
  float e = __expf(h - mx);
  red[t] = e; __syncthreads();
  for (int off = 128; off > 0; off >>= 1) {
    if (t < off) red[t] += red[t + off];
    __syncthreads();
  }
  float s = red[0];
  sh[t] = e / s;
  __syncthreads();
  if (t < KF) {
    float cr = 0.0f, ci = 0.0f;
    for (int j = 0; j < DD; ++j) {
      const int m = (t * j) & 255;
      const float p = sh[j];
      cr = fmaf(p, tc[m], cr);
      ci = fmaf(p, ts[m], ci);     // +sum p*sin; negate at store
    }
    const float sl = slog[b];
    const float sg = 1.0f / (1.0f + __expf(-sl));
    const float q = fmaf(2.0f, sg, -1.0f);
    ((v2f*)Q)[b * KF + t] = (v2f){q * cr, -q * ci};
  }
}

// ---------------- kernel 1: chunk transfer operators -----------------------------------------
// blocks 0..1023: (chunk p = blk>>1, k = (blk&1)*64 + t), complex path, Q staged in LDS
// blocks 1024..1031: k=128 real path, lane = chunk
__global__ __launch_bounds__(64, 1) void kchunk(const int* __restrict__ seq,
                                                const float* __restrict__ Qf,
                                                float* __restrict__ ops,
                                                float* __restrict__ ops128) {
  const int blk = blockIdx.x;
  const int t = threadIdx.x;
  __shared__ v2f Qlds[32 * 64];          // [c][l][lane] : flat (c*8 + l)*64 + lane; 16 KB
  if (blk < NCHUNK * 2) {
    const int p = blk >> 1;
    const int k = (blk & 1) * 64 + t;    // 0..127
    const v2f* Q2 = (const v2f*)Qf;
#pragma unroll
    for (int lc = 0; lc < 32; ++lc) {    // lc = l*4 + c
      const int c = lc & 3, l = lc >> 2;
      Qlds[(c * 8 + l) * 64 + t] = Q2[lc * KF + k];
    }
    __syncthreads();

    v2f G[NE1];
#pragma unroll
    for (int e = 0; e < NE1; ++e) G[e] = (v2f){0.0f, 0.0f};
#pragma unroll
    for (int l = 0; l <= LL; ++l) G[IDX(l, l)] = (v2f){1.0f, 0.0f};

    const int base = p * CLEN;
    const int4* sq = (const int4*)(seq + base);
#pragma unroll 1
    for (int q4 = 0; q4 < CLEN / 4; ++q4) {
      const int4 cv = sq[q4];
      const int cc[4] = {cv.x, cv.y, cv.z, cv.w};
#pragma unroll
      for (int r = 0; r < 4; ++r) {
        const int i = base + q4 * 4 + r;
        const float inv = 1.0f / (float)(i + 1);
        float z[LL + 1];
        z[0] = 0.0f;
#pragma unroll
        for (int l = 1; l <= LL; ++l) z[l] = (float)l * inv;
        if (i + 1 < LL) {                 // uniform; true only for chunk 0 steps 0..6
#pragma unroll
          for (int l = 1; l <= LL; ++l) if (l > i + 1) z[l] = 0.0f;
        }
        const v2f* qbase = &Qlds[cc[r] * 8 * 64 + t];   // entry l at qbase[l*64]
#pragma unroll
        for (int l = LL; l >= 1; --l) {  // descending: row l reads OLD row l-1
          const float zl = z[l], oz = 1.0f - zl;
          const v2f q = qbase[(l - 1) * 64];
          const v2f zq = zl * q;
          const float zqx = zq.x;
          const v2f zqn = {-zq.y, zq.y};
          G[IDX(l, l)] *= oz;
#pragma unroll
          for (int l1 = 0; l1 < l; ++l1) {
            const v2f H = G[IDX(l - 1, l1)];
            v2f tv = oz * G[IDX(l, l1)];
            tv += zqx * H;
            tv += zqn * vswap(H);
            G[IDX(l, l1)] = tv;
          }
        }
      }
    }
    v2f* O2 = (v2f*)ops;
#pragma unroll
    for (int e = 0; e < NE; ++e) O2[((size_t)p * NE + e) * KH + k] = G[e + 1];
  } else {
    // k = 128 (Nyquist, real Q); lane = chunk
    const int p = (blk - NCHUNK * 2) * 64 + t;   // 0..511
    float Q8[LL * AA];
#pragma unroll
    for (int lc = 0; lc < LL * AA; ++lc) Q8[lc] = Qf[(lc * KF + KH) * 2];
    float G[NE1];
#pragma unroll
    for (int e = 0; e < NE1; ++e) G[e] = 0.0f;
#pragma unroll
    for (int l = 0; l <= LL; ++l) G[IDX(l, l)] = 1.0f;

    const int base = p * CLEN;
    for (int s2 = 0; s2 < CLEN; ++s2) {
      const int i = base + s2;            // per-lane
      const int c = seq[i];
      const float inv = 1.0f / (float)(i + 1);
      float z[LL + 1];
      z[0] = 0.0f;
#pragma unroll
      for (int l = 1; l <= LL; ++l) z[l] = (l <= i + 1) ? (float)l * inv : 0.0f;
      float Qs[LL];
#pragma unroll
      for (int l = 0; l < LL; ++l) {
        const float qa = (c & 1) ? Q8[l * AA + 1] : Q8[l * AA + 0];
        const float qb = (c & 1) ? Q8[l * AA + 3] : Q8[l * AA + 2];
        Qs[l] = (c & 2) ? qb : qa;
      }
#pragma unroll
      for (int l = LL; l >= 1; --l) {
        const float zl = z[l], oz = 1.0f - zl;
        const float zq = zl * Qs[l - 1];
        G[IDX(l, l)] *= oz;
#pragma unroll
        for (int l1 = 0; l1 < l; ++l1)
          G[IDX(l, l1)] = fmaf(zq, G[IDX(l - 1, l1)], oz * G[IDX(l, l1)]);
      }
    }
#pragma unroll
    for (int e = 0; e < NE; ++e) ops128[e * NCHUNK + p] = G[e + 1];
  }
}

// ---------------- kernel 2: serial combine 8 consecutive ops (512 -> 64) ----------------------
__global__ __launch_bounds__(64, 1) void kcomb(const float* __restrict__ in,
                                               float* __restrict__ out,
                                               const float* __restrict__ in128,
                                               float* __restrict__ out128) {
  const int blk = blockIdx.x;
  const int t = threadIdx.x;
  if (blk < 128) {
    const int g = blk >> 1;
    const int k = (blk & 1) * 64 + t;
    const v2f* I2 = (const v2f*)in;
    v2f A[NE1];
    A[0] = (v2f){1.0f, 0.0f};
#pragma unroll
    for (int e = 0; e < NE; ++e) A[e + 1] = I2[((size_t)(g * 8) * NE + e) * KH + k];
#pragma unroll 1
    for (int j = 1; j < 8; ++j) {
      v2f B[NE1];
      B[0] = (v2f){1.0f, 0.0f};
#pragma unroll
      for (int e = 0; e < NE; ++e) B[e + 1] = I2[((size_t)(g * 8 + j) * NE + e) * KH + k];
      cmatmul(A, B);
    }
    v2f* O2 = (v2f*)out;
#pragma unroll
    for (int e = 0; e < NE; ++e) O2[((size_t)g * NE + e) * KH + k] = A[e + 1];
  } else {
    const int g = t;                      // 0..63
    float A[NE1];
    A[0] = 1.0f;
#pragma unroll
    for (int e = 0; e < NE; ++e) A[e + 1] = in128[e * NCHUNK + g * 8];
#pragma unroll 1
    for (int j = 1; j < 8; ++j) {
      float B[NE1];
      B[0] = 1.0f;
#pragma unroll
      for (int e = 0; e < NE; ++e) B[e + 1] = in128[e * NCHUNK + g * 8 + j];
      rmatmul(A, B);
    }
#pragma unroll
    for (int e = 0; e < NE; ++e) out128[e * NGRP + g] = A[e + 1];
  }
}

// ---------------- kernel 3: per-k in-LDS binary tree (bit-reversed placement) -----------------
// leaf for time-index t stored at slot bitrev6(t); level pairing (s, s+half) is then
// adjacent-in-time with all active reads/writes on CONSECUTIVE slots (bank-friendly).
__global__ __launch_bounds__(64, 1) void ktree(const float* __restrict__ in,
                                               const float* __restrict__ in128,
                                               float* __restrict__ v) {
  const int blk = blockIdx.x;
  const int t = threadIdx.x;
  __shared__ v2f nodes[NGRP * NE1];      // stride 45 v2f; 23 KB
  const int slot = (int)(__brev((unsigned)t) >> 26);   // bitrev6
  if (blk < KH) {
    const int k = blk;
    const v2f* I2 = (const v2f*)in;
    {
      v2f* np = &nodes[slot * NE1];
      np[0] = (v2f){1.0f, 0.0f};
#pragma unroll
      for (int e = 0; e < NE; ++e) np[e + 1] = I2[((size_t)t * NE + e) * KH + k];
    }
    __syncthreads();
#pragma unroll
    for (int half = 32; half >= 1; half >>= 1) {
      if (t < half) {
        v2f A[NE1], B[NE1];
#pragma unroll
        for (int e = 0; e < NE1; ++e) { A[e] = nodes[t * NE1 + e]; B[e] = nodes[(t + half) * NE1 + e]; }
        cmatmul(A, B);                   // A <- B*A (later * earlier)
#pragma unroll
        for (int e = 0; e < NE1; ++e) nodes[t * NE1 + e] = A[e];
      }
      __syncthreads();
    }
    if (t == 0) ((v2f*)v)[k] = nodes[IDX(LL, 0)];
  } else {
    float* fl = (float*)&nodes[0];       // real tree, stride 45 floats (11.5 KB)
    {
      float* np = &fl[slot * NE1];
      np[0] = 1.0f;
#pragma unroll
      for (int e = 0; e < NE; ++e) np[e + 1] = in128[e * NGRP + t];
    }
    __syncthreads();
#pragma unroll
    for (int half = 32; half >= 1; half >>= 1) {
      if (t < half) {
        float A[NE1], B[NE1];
#pragma unroll
        for (int e = 0; e < NE1; ++e) { A[e] = fl[t * NE1 + e]; B[e] = fl[(t + half) * NE1 + e]; }
        rmatmul(A, B);
#pragma unroll
        for (int e = 0; e < NE1; ++e) fl[t * NE1 + e] = A[e];
      }
      __syncthreads();
    }
    if (t == 0) ((v2f*)v)[KH] = (v2f){fl[IDX(LL, 0)], 0.0f};
  }
}

// ---------------- kernel 4: inverse real DFT --------------------------------------------------
__global__ __launch_bounds__(256) void kdft(const float* __restrict__ v,
                                            float* __restrict__ out) {
  const int t = threadIdx.x;
  __shared__ float tc[DD], ts[DD], vr[KF], vi[KF];
  {
    float sn, cs;
    __sincosf((float)t * TWO_PI_256, &sn, &cs);
    tc[t] = cs; ts[t] = sn;
  }
  if (t < KF) {
    v2f vv = ((const v2f*)v)[t];
    vr[t] = vv.x; vi[t] = vv.y;
  }
  __syncthreads();
  float sum = vr[0] + ((t & 1) ? -vr[KH] : vr[KH]);
  for (int k2 = 1; k2 < KH; ++k2) {
    const int m = (t * k2) & 255;
    sum = fmaf(2.0f * vr[k2], tc[m], sum);
    sum = fmaf(-2.0f * vi[k2], ts[m], sum);
  }
  out[t] = sum * (1.0f / 256.0f);
}

extern "C" void kernel_launch(void* const* d_in, const int* in_sizes, int n_in,
                              void* d_out, int out_size, void* d_ws, size_t ws_size,
                              hipStream_t stream) {
  (void)in_sizes; (void)n_in; (void)out_size; (void)ws_size;
  const int*   seq  = (const int*)d_in[0];
  const float* hemb = (const float*)d_in[1];
  const float* slog = (const float*)d_in[2];
  float* ws  = (float*)d_ws;
  float* Q   = ws + Q_OFF;
  float* ops = ws + OPS_OFF;
  float* s1  = ws + S1_OFF;
  float* r0  = ws + R0_OFF;
  float* r1  = ws + R1_OFF;
  float* vv  = ws + V_OFF;
  float* o   = (float*)d_out;

  hipLaunchKernelGGL(kq,     dim3(LL * AA), dim3(256), 0, stream, hemb, slog, Q);
  hipLaunchKernelGGL(kchunk, dim3(NCHUNK * 2 + NCHUNK / 64), dim3(64), 0, stream, seq, Q, ops, r0);
  hipLaunchKernelGGL(kcomb,  dim3(129), dim3(64), 0, stream, ops, s1, r0, r1);
  hipLaunchKernelGGL(ktree,  dim3(129), dim3(64), 0, stream, s1, r1, vv);
  hipLaunchKernelGGL(kdft,   dim3(1), dim3(256), 0, stream, vv, o);
}

// Round 5
// 132.000 us; speedup vs baseline: 1.0760x; 1.0104x over previous
//
#include <hip/hip_runtime.h>
#include <math.h>

#define LL 8
#define AA 4
#define DD 256
#define KF 129            // frequencies 0..128
#define KH 128            // complex path k=0..127; k=128 real
#define NCHUNK 512
#define CLEN 32           // 16384 / 512
#define NGRP 64           // groups after kcomb (512 / 8)
#define NE 44             // stored complex entries per operator (rows 1..8)
#define NE1 45            // including implicit row 0

#define IDX(l,l1) ((((l)*((l)+1))/2) + (l1))

typedef float v2f __attribute__((ext_vector_type(2)));

// ws layout in floats (~26 MB)
#define Q_OFF   0
#define OPS_OFF (Q_OFF + 32*KF*2)                 // ops: [p][e][k]   (coalesced across k)
#define S1_OFF  (OPS_OFF + NCHUNK*NE*KH*2)       // s1:  [k][g][e]   (contiguous per k)
#define R0_OFF  (S1_OFF + KH*NGRP*NE*2)
#define R1_OFF  (R0_OFF + NE*NCHUNK)
#define V_OFF   (R1_OFF + NE*NGRP)

#define TWO_PI_256 0.0245436926061702596754894014319f

__device__ __forceinline__ v2f vswap(v2f a) { return __builtin_shufflevector(a, a, 1, 0); }

// A <- B * A (9x9 unit-row0 lower-triangular complex)
__device__ __forceinline__ void cmatmul(v2f (&A)[NE1], const v2f (&B)[NE1]) {
#pragma unroll
  for (int l2 = LL; l2 >= 1; --l2) {
    v2f C[LL + 1];
#pragma unroll
    for (int l1 = 0; l1 <= l2; ++l1) C[l1] = (v2f){0.0f, 0.0f};
#pragma unroll
    for (int m = 0; m <= l2; ++m) {
      const v2f bm = B[IDX(l2, m)];
      const float bs = bm.x;
      const v2f bn = {-bm.y, bm.y};
#pragma unroll
      for (int l1 = 0; l1 <= m; ++l1) {
        const v2f Am = A[IDX(m, l1)];
        C[l1] += bs * Am;
        C[l1] += bn * vswap(Am);
      }
    }
#pragma unroll
    for (int l1 = 0; l1 <= l2; ++l1) A[IDX(l2, l1)] = C[l1];
  }
}

// A <- B * A (real)
__device__ __forceinline__ void rmatmul(float (&A)[NE1], const float (&B)[NE1]) {
#pragma unroll
  for (int l2 = LL; l2 >= 1; --l2) {
    float C[LL + 1];
#pragma unroll
    for (int l1 = 0; l1 <= l2; ++l1) C[l1] = 0.0f;
#pragma unroll
    for (int m = 0; m <= l2; ++m) {
      const float bs = B[IDX(l2, m)];
#pragma unroll
      for (int l1 = 0; l1 <= m; ++l1) C[l1] = fmaf(bs, A[IDX(m, l1)], C[l1]);
    }
#pragma unroll
    for (int l1 = 0; l1 <= l2; ++l1) A[IDX(l2, l1)] = C[l1];
  }
}

// ---------------- kernel 0: Q[l][c][k] = (2*sigmoid-1) * DFT_k(softmax(hash_emb[l,c,:])) ------
__global__ __launch_bounds__(256) void kq(const float* __restrict__ hemb,
                                          const float* __restrict__ slog,
                                          float* __restrict__ Q) {
  const int b = blockIdx.x;   // b = l*4 + c
  const int t = threadIdx.x;
  __shared__ float sh[DD], tc[DD], ts[DD], red[256];
  {
    float sn, cs;
    __sincosf((float)t * TWO_PI_256, &sn, &cs);
    tc[t] = cs; ts[t] = sn;
  }
  float h = hemb[b * DD + t];
  red[t] = h; __syncthreads();
  for (int off = 128; off > 0; off >>= 1) {
    if (t < off) red[t] = fmaxf(red[t], red[t + off]);
    __syncthreads();
  }
  float mx = red[0]; __syncthreads();
  float e = __expf(h - mx);
  red[t] = e; __syncthreads();
  for (int off = 128; off > 0; off >>= 1) {
    if (t < off) red[t] += red[t + off];
    __syncthreads();
  }
  float s = red[0];
  sh[t] = e / s;
  __syncthreads();
  if (t < KF) {
    float cr = 0.0f, ci = 0.0f;
    for (int j = 0; j < DD; ++j) {
      const int m = (t * j) & 255;
      const float p = sh[j];
      cr = fmaf(p, tc[m], cr);
      ci = fmaf(p, ts[m], ci);
    }
    const float sl = slog[b];
    const float sg = 1.0f / (1.0f + __expf(-sl));
    const float q = fmaf(2.0f, sg, -1.0f);
    ((v2f*)Q)[b * KF + t] = (v2f){q * cr, -q * ci};
  }
}

// ---------------- kernel 1: chunk transfer operators -----------------------------------------
__device__ __forceinline__ void loadq(v2f (&q)[LL], const v2f* Qt, int c) {
  const v2f* qb = Qt + c * (LL * 64);
#pragma unroll
  for (int l = 0; l < LL; ++l) q[l] = qb[l * 64];
}

__device__ __forceinline__ void cstep_q(v2f (&G)[NE1], const v2f (&q)[LL],
                                        const float (&z)[LL + 1]) {
#pragma unroll
  for (int l = LL; l >= 1; --l) {          // descending: row l reads OLD row l-1
    const float zl = z[l], oz = 1.0f - zl;
    const v2f zq = zl * q[l - 1];
    const float zqx = zq.x;
    const v2f zqn = {-zq.y, zq.y};
    G[IDX(l, l)] *= oz;
#pragma unroll
    for (int l1 = 0; l1 < l; ++l1) {
      const v2f H = G[IDX(l - 1, l1)];
      v2f tv = oz * G[IDX(l, l1)];
      tv += zqx * H;
      tv += zqn * vswap(H);
      G[IDX(l, l1)] = tv;
    }
  }
}

__global__ __launch_bounds__(64, 1) void kchunk(const int* __restrict__ seq,
                                                const float* __restrict__ Qf,
                                                float* __restrict__ ops,
                                                float* __restrict__ ops128) {
  const int blk = blockIdx.x;
  const int t = threadIdx.x;
  __shared__ v2f Qlds[AA * LL * 64];     // [c][l][lane]; 16 KB
  if (blk < NCHUNK * 2) {
    const int p = blk >> 1;
    const int k = (blk & 1) * 64 + t;    // 0..127
    const v2f* Q2 = (const v2f*)Qf;
#pragma unroll
    for (int lc = 0; lc < 32; ++lc) {    // lc = l*4 + c
      const int c = lc & 3, l = lc >> 2;
      Qlds[(c * LL + l) * 64 + t] = Q2[lc * KF + k];
    }
    __syncthreads();

    v2f G[NE1];
#pragma unroll
    for (int e = 0; e < NE1; ++e) G[e] = (v2f){0.0f, 0.0f};
#pragma unroll
    for (int l = 0; l <= LL; ++l) G[IDX(l, l)] = (v2f){1.0f, 0.0f};

    const v2f* Qt = &Qlds[t];
    const int base = p * CLEN;
    const int4* sq = (const int4*)(seq + base);
    int4 cv = sq[0];
    v2f qc[LL];
    loadq(qc, Qt, cv.x);                 // prefetch step 0's q
#pragma unroll 1
    for (int q4 = 0; q4 < CLEN / 4; ++q4) {
      const int cc[4] = {cv.x, cv.y, cv.z, cv.w};
      const int4 cvn = (q4 + 1 < CLEN / 4) ? sq[q4 + 1] : cv;   // prefetch next symbols
#pragma unroll
      for (int r = 0; r < 4; ++r) {
        const int i = base + q4 * 4 + r;
        const float inv = 1.0f / (float)(i + 1);
        float z[LL + 1];
        z[0] = 0.0f;
#pragma unroll
        for (int l = 1; l <= LL; ++l) z[l] = (float)l * inv;
        if (i + 1 < LL) {                // uniform; only chunk 0 steps 0..6
#pragma unroll
          for (int l = 1; l <= LL; ++l) if (l > i + 1) z[l] = 0.0f;
        }
        // prefetch next step's q while computing this step
        const int cnext = (r < 3) ? cc[r + 1] : cvn.x;
        v2f qn[LL];
        loadq(qn, Qt, cnext);
        cstep_q(G, qc, z);
#pragma unroll
        for (int l = 0; l < LL; ++l) qc[l] = qn[l];
      }
      cv = cvn;
    }
    v2f* O2 = (v2f*)ops;
#pragma unroll
    for (int e = 0; e < NE; ++e) O2[((size_t)p * NE + e) * KH + k] = G[e + 1];
  } else {
    // k = 128 (Nyquist, real Q); lane = chunk
    const int p = (blk - NCHUNK * 2) * 64 + t;   // 0..511
    float Q8[LL * AA];
#pragma unroll
    for (int lc = 0; lc < LL * AA; ++lc) Q8[lc] = Qf[(lc * KF + KH) * 2];
    float G[NE1];
#pragma unroll
    for (int e = 0; e < NE1; ++e) G[e] = 0.0f;
#pragma unroll
    for (int l = 0; l <= LL; ++l) G[IDX(l, l)] = 1.0f;

    const int base = p * CLEN;
    for (int s2 = 0; s2 < CLEN; ++s2) {
      const int i = base + s2;
      const int c = seq[i];
      const float inv = 1.0f / (float)(i + 1);
      float z[LL + 1];
      z[0] = 0.0f;
#pragma unroll
      for (int l = 1; l <= LL; ++l) z[l] = (l <= i + 1) ? (float)l * inv : 0.0f;
      float Qs[LL];
#pragma unroll
      for (int l = 0; l < LL; ++l) {
        const float qa = (c & 1) ? Q8[l * AA + 1] : Q8[l * AA + 0];
        const float qb = (c & 1) ? Q8[l * AA + 3] : Q8[l * AA + 2];
        Qs[l] = (c & 2) ? qb : qa;
      }
#pragma unroll
      for (int l = LL; l >= 1; --l) {
        const float zl = z[l], oz = 1.0f - zl;
        const float zq = zl * Qs[l - 1];
        G[IDX(l, l)] *= oz;
#pragma unroll
        for (int l1 = 0; l1 < l; ++l1)
          G[IDX(l, l1)] = fmaf(zq, G[IDX(l - 1, l1)], oz * G[IDX(l, l1)]);
      }
    }
#pragma unroll
    for (int e = 0; e < NE; ++e) ops128[e * NCHUNK + p] = G[e + 1];
  }
}

// ---------------- kernel 2: combine 8 consecutive ops (512 -> 64), prefetched ----------------
// complex output: s1[k][g][e]  (contiguous 44 v2f per (k,g); per-k region contiguous)
__global__ __launch_bounds__(64, 1) void kcomb(const float* __restrict__ in,
                                               float* __restrict__ out,
                                               const float* __restrict__ in128,
                                               float* __restrict__ out128) {
  const int blk = blockIdx.x;
  const int t = threadIdx.x;
  if (blk < 128) {
    const int g = blk >> 1;
    const int k = (blk & 1) * 64 + t;
    const v2f* I2 = (const v2f*)in;
    v2f A[NE1];
    A[0] = (v2f){1.0f, 0.0f};
#pragma unroll
    for (int e = 0; e < NE; ++e) A[e + 1] = I2[((size_t)(g * 8) * NE + e) * KH + k];
    v2f Bn[NE1];
    Bn[0] = (v2f){1.0f, 0.0f};
#pragma unroll
    for (int e = 0; e < NE; ++e) Bn[e + 1] = I2[((size_t)(g * 8 + 1) * NE + e) * KH + k];
#pragma unroll
    for (int j = 1; j < 8; ++j) {
      v2f Bc[NE1];
#pragma unroll
      for (int e = 0; e < NE1; ++e) Bc[e] = Bn[e];
      if (j < 7) {                       // prefetch j+1 before the matmul
#pragma unroll
        for (int e = 0; e < NE; ++e) Bn[e + 1] = I2[((size_t)(g * 8 + j + 1) * NE + e) * KH + k];
      }
      cmatmul(A, Bc);
    }
    v2f* O2 = (v2f*)out;
#pragma unroll
    for (int e = 0; e < NE; ++e) O2[((size_t)k * NGRP + g) * NE + e] = A[e + 1];
  } else {
    const int g = t;                     // 0..63
    float A[NE1];
    A[0] = 1.0f;
#pragma unroll
    for (int e = 0; e < NE; ++e) A[e + 1] = in128[e * NCHUNK + g * 8];
#pragma unroll 1
    for (int j = 1; j < 8; ++j) {
      float B[NE1];
      B[0] = 1.0f;
#pragma unroll
      for (int e = 0; e < NE; ++e) B[e + 1] = in128[e * NCHUNK + g * 8 + j];
      rmatmul(A, B);
    }
#pragma unroll
    for (int e = 0; e < NE; ++e) out128[e * NGRP + g] = A[e + 1];
  }
}

// ---------------- kernel 3: per-k in-LDS binary tree (bit-reversed placement) -----------------
__global__ __launch_bounds__(64, 1) void ktree(const float* __restrict__ in,
                                               const float* __restrict__ in128,
                                               float* __restrict__ v) {
  const int blk = blockIdx.x;
  const int t = threadIdx.x;
  __shared__ v2f nodes[NGRP * NE1];      // 23 KB
  const int slot = (int)(__brev((unsigned)t) >> 26);   // bitrev6(t)
  if (blk < KH) {
    const v2f* src = (const v2f*)in + (size_t)blk * NGRP * NE;   // contiguous 22.5 KB
    // cooperative coalesced load: op g's 44 entries by lanes t<44
#pragma unroll 4
    for (int g = 0; g < NGRP; ++g) {
      const int sg = (int)(__brev((unsigned)g) >> 26);
      if (t < NE) nodes[sg * NE1 + 1 + t] = src[(size_t)g * NE + t];
    }
    nodes[slot * NE1] = (v2f){1.0f, 0.0f};
    __syncthreads();
#pragma unroll
    for (int half = 32; half >= 1; half >>= 1) {
      if (t < half) {
        v2f A[NE1], B[NE1];
#pragma unroll
        for (int e = 0; e < NE1; ++e) { A[e] = nodes[t * NE1 + e]; B[e] = nodes[(t + half) * NE1 + e]; }
        cmatmul(A, B);                   // A <- B*A (later * earlier)
#pragma unroll
        for (int e = 0; e < NE1; ++e) nodes[t * NE1 + e] = A[e];
      }
      __syncthreads();
    }
    if (t == 0) ((v2f*)v)[blk] = nodes[IDX(LL, 0)];
  } else {
    float* fl = (float*)&nodes[0];       // real tree, stride NE1 floats
    {
      float* np = &fl[slot * NE1];
      np[0] = 1.0f;
#pragma unroll
      for (int e = 0; e < NE; ++e) np[e + 1] = in128[e * NGRP + t];
    }
    __syncthreads();
#pragma unroll
    for (int half = 32; half >= 1; half >>= 1) {
      if (t < half) {
        float A[NE1], B[NE1];
#pragma unroll
        for (int e = 0; e < NE1; ++e) { A[e] = fl[t * NE1 + e]; B[e] = fl[(t + half) * NE1 + e]; }
        rmatmul(A, B);
#pragma unroll
        for (int e = 0; e < NE1; ++e) fl[t * NE1 + e] = A[e];
      }
      __syncthreads();
    }
    if (t == 0) ((v2f*)v)[KH] = (v2f){fl[IDX(LL, 0)], 0.0f};
  }
}

// ---------------- kernel 4: inverse real DFT --------------------------------------------------
__global__ __launch_bounds__(256) void kdft(const float* __restrict__ v,
                                            float* __restrict__ out) {
  const int t = threadIdx.x;
  __shared__ float tc[DD], ts[DD], vr[KF], vi[KF];
  {
    float sn, cs;
    __sincosf((float)t * TWO_PI_256, &sn, &cs);
    tc[t] = cs; ts[t] = sn;
  }
  if (t < KF) {
    v2f vv = ((const v2f*)v)[t];
    vr[t] = vv.x; vi[t] = vv.y;
  }
  __syncthreads();
  float sum = vr[0] + ((t & 1) ? -vr[KH] : vr[KH]);
  for (int k2 = 1; k2 < KH; ++k2) {
    const int m = (t * k2) & 255;
    sum = fmaf(2.0f * vr[k2], tc[m], sum);
    sum = fmaf(-2.0f * vi[k2], ts[m], sum);
  }
  out[t] = sum * (1.0f / 256.0f);
}

extern "C" void kernel_launch(void* const* d_in, const int* in_sizes, int n_in,
                              void* d_out, int out_size, void* d_ws, size_t ws_size,
                              hipStream_t stream) {
  (void)in_sizes; (void)n_in; (void)out_size; (void)ws_size;
  const int*   seq  = (const int*)d_in[0];
  const float* hemb = (const float*)d_in[1];
  const float* slog = (const float*)d_in[2];
  float* ws  = (float*)d_ws;
  float* Q   = ws + Q_OFF;
  float* ops = ws + OPS_OFF;
  float* s1  = ws + S1_OFF;
  float* r0  = ws + R0_OFF;
  float* r1  = ws + R1_OFF;
  float* vv  = ws + V_OFF;
  float* o   = (float*)d_out;

  hipLaunchKernelGGL(kq,     dim3(LL * AA), dim3(256), 0, stream, hemb, slog, Q);
  hipLaunchKernelGGL(kchunk, dim3(NCHUNK * 2 + NCHUNK / 64), dim3(64), 0, stream, seq, Q, ops, r0);
  hipLaunchKernelGGL(kcomb,  dim3(129), dim3(64), 0, stream, ops, s1, r0, r1);
  hipLaunchKernelGGL(ktree,  dim3(129), dim3(64), 0, stream, s1, r1, vv);
  hipLaunchKernelGGL(kdft,   dim3(1), dim3(256), 0, stream, vv, o);
}